// Round 9
// baseline (44.266 us; speedup 1.0000x reference)
//
#include <hip/hip_runtime.h>

#define D 64
#define L 10
#define C 256
#define G 2
#define SWB 72  // bf16 LDS row stride in shorts (144 B, 16B-aligned)

typedef __attribute__((ext_vector_type(8))) short bf16x8;
typedef __attribute__((ext_vector_type(4))) short short4v;
typedef __attribute__((ext_vector_type(4))) float f32x4;

__device__ inline short f2bf(float f) {
  unsigned u = __float_as_uint(f);
  u = (u + 0x7FFFu + ((u >> 16) & 1u)) >> 16;
  return (short)u;
}
__device__ inline float4 add3(float4 a, float4 b, float4 c) {
  return make_float4(a.x + b.x + c.x, a.y + b.y + c.y, a.z + b.z + c.z, a.w + b.w + c.w);
}
__device__ inline short4v f2bf4(float4 a) {
  short4v r;
  r[0] = f2bf(a.x); r[1] = f2bf(a.y); r[2] = f2bf(a.z); r[3] = f2bf(a.w);
  return r;
}

// Coalesced pre (verified R8). Bf[c][k] = bf16(0.125*(cl@Wk@Wq^T)[c][k]),
// Bf[c][64+d] = bf16((cl@Wv)[c][d]).
__global__ __launch_bounds__(256) void pre(const float* __restrict__ cl,
                                           const float* __restrict__ Wk,
                                           const float* __restrict__ Wq,
                                           const float* __restrict__ Wv,
                                           short* __restrict__ Bf) {
  __shared__ float s_cl[4 * 64];
  __shared__ float s_kc[4 * 64];
  __shared__ float s_w[64 * 65];
  const int t = threadIdx.x;
  const int bh = blockIdx.x >> 6, cb = blockIdx.x & 63;
  const int c0 = cb * 4;
  const int r = t >> 6, j = t & 63;

  s_cl[t] = cl[c0 * 64 + t];
  if (bh == 0) {
#pragma unroll
    for (int i = 0; i < 4; ++i) {
      int e = i * 256 + t;
      float4 v = ((const float4*)Wq)[e];
      int k = e >> 4, q = e & 15;
      float* dst = &s_w[k * 65 + q * 4];
      dst[0] = v.x; dst[1] = v.y; dst[2] = v.z; dst[3] = v.w;
    }
  }
  __syncthreads();

  const float* __restrict__ Wx = bh ? Wv : Wk;
  float acc = 0.f;
#pragma unroll 8
  for (int m = 0; m < 64; ++m) acc += s_cl[r * 64 + m] * Wx[m * 64 + j];

  if (bh == 1) {
    Bf[(c0 + r) * 128 + 64 + j] = f2bf(acc);
    return;
  }
  s_kc[t] = acc;
  __syncthreads();

  float o = 0.f;
#pragma unroll 8
  for (int jj = 0; jj < 64; ++jj) o += s_kc[r * 64 + jj] * s_w[j * 65 + jj];
  Bf[(c0 + r) * 128 + j] = f2bf(0.125f * o);
}

// G=2 packing: short-tile mt = user mt (A row r = l, rows 10-15 zero);
// ue tile rows 0..1 = users. C/D row = kb*4+jj = l; vu from cu[0]/cu[1].
__global__ __launch_bounds__(256, 6) void filter_main(
    const int* __restrict__ items, const float* __restrict__ te,
    const float* __restrict__ ue_g, const float* __restrict__ ie_g,
    const float* __restrict__ wf_g, const short* __restrict__ Bf,
    const int* __restrict__ users, const int* __restrict__ pos_items,
    const int* __restrict__ neg_items, const float* __restrict__ a1p,
    const float* __restrict__ a2p, const float* __restrict__ a3p,
    float* __restrict__ out, int B) {
  __shared__ short s_shb[20 * SWB];   // short rows, bf16
  __shared__ short s_ueb[G * SWB];    // ue rows, bf16
  __shared__ float2 s_red[G][12][4];  // [user][l][wave] -> (S,T)

  const int tid = threadIdx.x, w = tid >> 6, lane = tid & 63;
  const int col16 = lane & 15, kb = lane >> 4;
  const int b2 = blockIdx.x * G;
  const int BD = B * D;

  const int us0 = users[b2], us1 = users[b2 + 1];

  // per-user long-latency loads: only waves 0,1 (their own user)
  float uev = 0.f, posv = 0.f, negv = 0.f;
  float wfv[L];
  const int usw = (w == 0) ? us0 : us1;
  if (w < G) {
    uev = ue_g[usw * D + lane];
    posv = ie_g[pos_items[b2 + w] * D + lane];
    negv = ie_g[neg_items[b2 + w] * D + lane];
#pragma unroll
    for (int l = 0; l < L; ++l) wfv[l] = wf_g[(usw * L + l) * D + lane];
    s_ueb[w * SWB + lane] = f2bf(uev);
  }

  // ---- coalesced staging: short[row] = te + ie + ue -> bf16 LDS (20 rows)
  {
    const float4* te4 = (const float4*)te;
    const float4* ie4 = (const float4*)ie_g;
    const float4* ue4 = (const float4*)ue_g;
    const int grp = tid >> 4, j = tid & 15;
#pragma unroll
    for (int it = 0; it < 2; ++it) {
      int row = it * 16 + grp;
      if (row < 20) {
        int g = row / 10, l = row - g * 10;
        int uu = g ? us1 : us0;
        int itm = items[uu * L + l];
        float4 t = te4[(uu * L + l) * 16 + j];
        float4 e = ie4[itm * 16 + j];
        float4 uf = ue4[uu * 16 + j];
        *(short4v*)&s_shb[row * SWB + j * 4] = f2bf4(add3(t, e, uf));
      }
    }
  }
  __syncthreads();

  // ---- A fragments: row l = col16 (zero for l >= 10)
  bf16x8 a00 = {}, a01 = {}, a10 = {}, a11 = {}, au0 = {}, au1 = {};
  if (col16 < L) {
    const bf16x8* rp = (const bf16x8*)&s_shb[col16 * SWB];
    a00 = rp[kb];
    a01 = rp[4 + kb];
    const bf16x8* rp1 = (const bf16x8*)&s_shb[(10 + col16) * SWB];
    a10 = rp1[kb];
    a11 = rp1[4 + kb];
  }
  if (col16 < G) {
    const bf16x8* rp = (const bf16x8*)&s_ueb[col16 * SWB];
    au0 = rp[kb];
    au1 = rp[4 + kb];
  }

  // ---- per-nt GEMM + softmax accumulation (no max-sub; fp32-safe range)
  float Sa[G][4], Ta[G][4];
#pragma unroll
  for (int mt = 0; mt < G; ++mt)
#pragma unroll
    for (int jj = 0; jj < 4; ++jj) { Sa[mt][jj] = 0.f; Ta[mt][jj] = 0.f; }

#pragma unroll
  for (int nt = 0; nt < 4; ++nt) {
    const bf16x8* bp = (const bf16x8*)(Bf + ((w * 4 + nt) * 16 + col16) * 128);
    bf16x8 b0 = bp[kb], b1 = bp[4 + kb], b2 = bp[8 + kb], b3 = bp[12 + kb];
    f32x4 z = {0.f, 0.f, 0.f, 0.f};
    f32x4 c0 = z, c1 = z, cu = z;
    c0 = __builtin_amdgcn_mfma_f32_16x16x32_bf16(a00, b0, c0, 0, 0, 0);
    c0 = __builtin_amdgcn_mfma_f32_16x16x32_bf16(a01, b1, c0, 0, 0, 0);
    c1 = __builtin_amdgcn_mfma_f32_16x16x32_bf16(a10, b0, c1, 0, 0, 0);
    c1 = __builtin_amdgcn_mfma_f32_16x16x32_bf16(a11, b1, c1, 0, 0, 0);
    cu = __builtin_amdgcn_mfma_f32_16x16x32_bf16(au0, b2, cu, 0, 0, 0);
    cu = __builtin_amdgcn_mfma_f32_16x16x32_bf16(au1, b3, cu, 0, 0, 0);
    // vu[g] at C/D row g: lanes kb=0, reg g -> static regs cu[0], cu[1]
    float vu0 = __shfl(cu[0], col16, 64);
    float vu1 = __shfl(cu[1], col16, 64);
#pragma unroll
    for (int mt = 0; mt < G; ++mt)
#pragma unroll
      for (int jj = 0; jj < 4; ++jj) {
        float sv = (mt == 0) ? c0[jj] : c1[jj];
        float e = __expf(sv);
        float vu = (mt == 0) ? vu0 : vu1;
        Sa[mt][jj] += e;
        Ta[mt][jj] += e * vu;
      }
  }

  // ---- reduce over col16, write per-wave stats (row l = kb*4+jj)
#pragma unroll
  for (int mt = 0; mt < G; ++mt)
#pragma unroll
    for (int jj = 0; jj < 4; ++jj) {
      float S = Sa[mt][jj], T = Ta[mt][jj];
      S += __shfl_xor(S, 1, 64); T += __shfl_xor(T, 1, 64);
      S += __shfl_xor(S, 2, 64); T += __shfl_xor(T, 2, 64);
      S += __shfl_xor(S, 4, 64); T += __shfl_xor(T, 4, 64);
      S += __shfl_xor(S, 8, 64); T += __shfl_xor(T, 8, 64);
      int l = kb * 4 + jj;
      if (col16 == 0 && l < 12) s_red[mt][l][w] = make_float2(S, T);
    }
  __syncthreads();

  // ---- waves 0,1 own their user: combine waves, s_l = T/S, nu, outputs
  if (w < G) {
    float nu = 0.f;
#pragma unroll
    for (int l = 0; l < L; ++l) {
      float2 p0 = s_red[w][l][0], p1 = s_red[w][l][1];
      float2 p2 = s_red[w][l][2], p3 = s_red[w][l][3];
      float S = (p0.x + p1.x) + (p2.x + p3.x);
      float T = (p0.y + p1.y) + (p2.y + p3.y);
      nu += T * __frcp_rn(S) * wfv[l];
    }
    const float a1 = *a1p, a2 = *a2p, a3 = *a3p;
    out[(b2 + w) * D + lane] = a3 * (a1 * uev + a2 * nu);
    out[BD + (b2 + w) * D + lane] = posv;
    out[2 * BD + (b2 + w) * D + lane] = negv;
  }
}

extern "C" void kernel_launch(void* const* d_in, const int* in_sizes, int n_in,
                              void* d_out, int out_size, void* d_ws, size_t ws_size,
                              hipStream_t stream) {
  const int* items = (const int*)d_in[0];
  const float* time_embs = (const float*)d_in[1];
  const float* user_emb = (const float*)d_in[2];
  const float* item_emb = (const float*)d_in[3];
  const float* cluster = (const float*)d_in[4];
  const float* wf = (const float*)d_in[5];
  const float* Wq = (const float*)d_in[6];
  const float* Wk = (const float*)d_in[7];
  const float* Wv = (const float*)d_in[8];
  const int* users = (const int*)d_in[9];
  const int* pos = (const int*)d_in[10];
  const int* neg = (const int*)d_in[11];
  const float* a1 = (const float*)d_in[12];
  const float* a2 = (const float*)d_in[13];
  const float* a3 = (const float*)d_in[14];
  const int B = in_sizes[9];

  short* Bf = (short*)d_ws;  // [C][128] bf16
  hipLaunchKernelGGL(pre, dim3(128), dim3(256), 0, stream,
                     cluster, Wk, Wq, Wv, Bf);
  hipLaunchKernelGGL(filter_main, dim3(B / G), dim3(256), 0, stream,
                     items, time_embs, user_emb, item_emb, wf, Bf,
                     users, pos, neg, a1, a2, a3, (float*)d_out, B);
}

// Round 10
// 30.280 us; speedup vs baseline: 1.4619x; 1.4619x over previous
//
#include <hip/hip_runtime.h>

#define D 64
#define L 10
#define C 256
#define G 4
#define SWB 72          // bf16 LDS row stride (144 B)
#define NROWS 44        // ws rows per user-group: 40 short + 4 ue
#define STAGE_ROWS 52   // + 4 pos + 4 neg handled in stage
#define PRE_BLOCKS 128

typedef __attribute__((ext_vector_type(8))) short bf16x8;
typedef __attribute__((ext_vector_type(4))) short short4v;
typedef __attribute__((ext_vector_type(4))) float f32x4;

__device__ inline short f2bf(float f) {
  unsigned u = __float_as_uint(f);
  u = (u + 0x7FFFu + ((u >> 16) & 1u)) >> 16;
  return (short)u;
}
__device__ inline float4 add3(float4 a, float4 b, float4 c) {
  return make_float4(a.x + b.x + c.x, a.y + b.y + c.y, a.z + b.z + c.z, a.w + b.w + c.w);
}
__device__ inline short4v f2bf4(float4 a) {
  short4v r;
  r[0] = f2bf(a.x); r[1] = f2bf(a.y); r[2] = f2bf(a.z); r[3] = f2bf(a.w);
  return r;
}

// Merged stage+pre kernel.
// Blocks 0..127: pre (R8-verified coalesced) -> Bf[c][0:64]=0.125*(cl@Wk@Wq^T),
//                Bf[c][64:128]=cl@Wv, both bf16.
// Blocks 128.. : flat gather/stage. rid = 16 row-slots/block over
//   NUG*52 rows: r<40 short rows -> ws (bf16); 40-43 ue rows -> ws (bf16);
//   44-47 pos -> out; 48-51 neg -> out. No barriers, no phase coupling.
__global__ __launch_bounds__(256) void stage_pre(
    const float* __restrict__ cl, const float* __restrict__ Wk,
    const float* __restrict__ Wq, const float* __restrict__ Wv,
    const int* __restrict__ items, const float* __restrict__ te,
    const float* __restrict__ ue_g, const float* __restrict__ ie_g,
    const int* __restrict__ users, const int* __restrict__ pos_items,
    const int* __restrict__ neg_items, short* __restrict__ Bf,
    short* __restrict__ wsrows, float* __restrict__ out, int B, int NUG) {
  __shared__ float s_cl[4 * 64];
  __shared__ float s_kc[4 * 64];
  __shared__ float s_w[64 * 65];
  const int t = threadIdx.x;

  if (blockIdx.x < PRE_BLOCKS) {
    const int bh = blockIdx.x >> 6, cb = blockIdx.x & 63;
    const int c0 = cb * 4;
    const int r = t >> 6, j = t & 63;
    s_cl[t] = cl[c0 * 64 + t];
    if (bh == 0) {
#pragma unroll
      for (int i = 0; i < 4; ++i) {
        int e = i * 256 + t;
        float4 v = ((const float4*)Wq)[e];
        int k = e >> 4, q = e & 15;
        float* dst = &s_w[k * 65 + q * 4];
        dst[0] = v.x; dst[1] = v.y; dst[2] = v.z; dst[3] = v.w;
      }
    }
    __syncthreads();
    const float* __restrict__ Wx = bh ? Wv : Wk;
    float acc = 0.f;
#pragma unroll 8
    for (int m = 0; m < 64; ++m) acc += s_cl[r * 64 + m] * Wx[m * 64 + j];
    if (bh == 1) {
      Bf[(c0 + r) * 128 + 64 + j] = f2bf(acc);
      return;
    }
    s_kc[t] = acc;
    __syncthreads();
    float o = 0.f;
#pragma unroll 8
    for (int jj = 0; jj < 64; ++jj) o += s_kc[r * 64 + jj] * s_w[j * 65 + jj];
    Bf[(c0 + r) * 128 + j] = f2bf(0.125f * o);
    return;
  }

  // ---- stage role
  const int sb = blockIdx.x - PRE_BLOCKS;
  const int rid = sb * 16 + (t >> 4);
  const int j = t & 15;
  const int ug = rid / STAGE_ROWS;
  const int r = rid - ug * STAGE_ROWS;
  if (ug >= NUG) return;
  const float4* te4 = (const float4*)te;
  const float4* ie4 = (const float4*)ie_g;
  const float4* ue4 = (const float4*)ue_g;
  const int BD = B * D;

  if (r < 40) {
    int g = r / 10, l = r - g * 10;
    int u = users[ug * G + g];
    int itm = items[u * L + l];
    float4 v = add3(te4[(u * L + l) * 16 + j], ie4[itm * 16 + j], ue4[u * 16 + j]);
    *(short4v*)&wsrows[(ug * NROWS + r) * 64 + j * 4] = f2bf4(v);
  } else if (r < 44) {
    int g = r - 40;
    int u = users[ug * G + g];
    *(short4v*)&wsrows[(ug * NROWS + 40 + g) * 64 + j * 4] = f2bf4(ue4[u * 16 + j]);
  } else if (r < 48) {
    int g = r - 44, row = ug * G + g;
    *(float4*)&out[BD + row * D + j * 4] = ie4[pos_items[row] * 16 + j];
  } else {
    int g = r - 48, row = ug * G + g;
    *(float4*)&out[2 * BD + row * D + j * 4] = ie4[neg_items[row] * 16 + j];
  }
}

// GEMM kernel: linear ws read -> LDS -> MFMA -> softmax stats -> epilogue.
// Row packing (verified R4-R8): A-tile row r=(qr*4+jr); p=mt*4+jr, g=p/3,
// sub=p%3, l=sub*4+qr. In C/D space (row=kb*4+jj): p=mt*4+jj, l=sub*4+kb.
__global__ __launch_bounds__(256, 4) void gemm_main(
    const short* __restrict__ wsrows, const short* __restrict__ Bf,
    const float* __restrict__ ue_g, const float* __restrict__ wf_g,
    const int* __restrict__ users, const float* __restrict__ a1p,
    const float* __restrict__ a2p, const float* __restrict__ a3p,
    float* __restrict__ out, int B) {
  __shared__ short s_shb[NROWS * SWB];
  __shared__ float2 s_red[G][12][4];

  const int tid = threadIdx.x, w = tid >> 6, lane = tid & 63;
  const int col16 = lane & 15, kb = lane >> 4;
  const int qr = col16 >> 2, jr = col16 & 3;
  const int b4 = blockIdx.x * G;

  // hoisted per-user loads (consumed in epilogue, hidden under GEMM)
  const int usw = users[b4 + w];
  const float uev = ue_g[usw * D + lane];
  float wfv[L];
#pragma unroll
  for (int l = 0; l < L; ++l) wfv[l] = wf_g[(usw * L + l) * D + lane];
  const float a1 = *a1p, a2 = *a2p, a3 = *a3p;

  // linear LDS copy: 44 rows x 128B from ws (L2/L3-hot, written by stage)
  {
    const int base = blockIdx.x * NROWS * 64;
#pragma unroll
    for (int pass = 0; pass < 2; ++pass) {
      int idx = pass * 256 + tid;
      int row = idx >> 3, ch = idx & 7;
      if (row < NROWS)
        *(bf16x8*)&s_shb[row * SWB + ch * 8] =
            *(const bf16x8*)&wsrows[base + row * 64 + ch * 8];
    }
  }
  __syncthreads();

  // ---- A fragments: pure ds_read_b128 from bf16 LDS
  bf16x8 a00, a01, a10, a11, a20, a21, au0 = {}, au1 = {};
#define FRAG(AV0, AV1, MT)                                                     \
  {                                                                            \
    int p = (MT)*4 + jr;                                                       \
    int g = p / 3;                                                             \
    int l = (p - g * 3) * 4 + qr;                                              \
    if (l < L) {                                                               \
      const bf16x8* rp = (const bf16x8*)&s_shb[(g * 10 + l) * SWB];            \
      AV0 = rp[kb];                                                            \
      AV1 = rp[4 + kb];                                                        \
    } else {                                                                   \
      AV0 = bf16x8{};                                                          \
      AV1 = bf16x8{};                                                          \
    }                                                                          \
  }
  FRAG(a00, a01, 0)
  FRAG(a10, a11, 1)
  FRAG(a20, a21, 2)
  if (col16 < G) {
    const bf16x8* rp = (const bf16x8*)&s_shb[(40 + col16) * SWB];
    au0 = rp[kb];
    au1 = rp[4 + kb];
  }

  // ---- per-nt GEMM + softmax accumulation (no max-sub; fp32-safe range)
  float Sa[3][4], Ta[3][4];
#pragma unroll
  for (int mt = 0; mt < 3; ++mt)
#pragma unroll
    for (int jj = 0; jj < 4; ++jj) { Sa[mt][jj] = 0.f; Ta[mt][jj] = 0.f; }

#pragma unroll
  for (int nt = 0; nt < 4; ++nt) {
    const bf16x8* bp = (const bf16x8*)(Bf + ((w * 4 + nt) * 16 + col16) * 128);
    bf16x8 b0 = bp[kb], b1 = bp[4 + kb], b2 = bp[8 + kb], b3 = bp[12 + kb];
    f32x4 z = {0.f, 0.f, 0.f, 0.f};
    f32x4 c0 = z, c1 = z, c2 = z, cu = z;
    c0 = __builtin_amdgcn_mfma_f32_16x16x32_bf16(a00, b0, c0, 0, 0, 0);
    c0 = __builtin_amdgcn_mfma_f32_16x16x32_bf16(a01, b1, c0, 0, 0, 0);
    c1 = __builtin_amdgcn_mfma_f32_16x16x32_bf16(a10, b0, c1, 0, 0, 0);
    c1 = __builtin_amdgcn_mfma_f32_16x16x32_bf16(a11, b1, c1, 0, 0, 0);
    c2 = __builtin_amdgcn_mfma_f32_16x16x32_bf16(a20, b0, c2, 0, 0, 0);
    c2 = __builtin_amdgcn_mfma_f32_16x16x32_bf16(a21, b1, c2, 0, 0, 0);
    cu = __builtin_amdgcn_mfma_f32_16x16x32_bf16(au0, b2, cu, 0, 0, 0);
    cu = __builtin_amdgcn_mfma_f32_16x16x32_bf16(au1, b3, cu, 0, 0, 0);
    float vu0 = __shfl(cu[0], col16, 64);
    float vu1 = __shfl(cu[1], col16, 64);
    float vu2 = __shfl(cu[2], col16, 64);
    float vu3 = __shfl(cu[3], col16, 64);
#pragma unroll
    for (int mt = 0; mt < 3; ++mt)
#pragma unroll
      for (int jj = 0; jj < 4; ++jj) {
        float sv = (mt == 0) ? c0[jj] : (mt == 1) ? c1[jj] : c2[jj];
        float e = __expf(sv);
        const int g = (mt * 4 + jj) / 3;  // compile-time
        float vu = (g == 0) ? vu0 : ((g == 1) ? vu1 : ((g == 2) ? vu2 : vu3));
        Sa[mt][jj] += e;
        Ta[mt][jj] += e * vu;
      }
  }

  // ---- reduce over col16, write per-wave stats
#pragma unroll
  for (int mt = 0; mt < 3; ++mt)
#pragma unroll
    for (int jj = 0; jj < 4; ++jj) {
      float S = Sa[mt][jj], T = Ta[mt][jj];
      S += __shfl_xor(S, 1, 64); T += __shfl_xor(T, 1, 64);
      S += __shfl_xor(S, 2, 64); T += __shfl_xor(T, 2, 64);
      S += __shfl_xor(S, 4, 64); T += __shfl_xor(T, 4, 64);
      S += __shfl_xor(S, 8, 64); T += __shfl_xor(T, 8, 64);
      if (col16 == 0) {
        const int g = (mt * 4 + jj) / 3, sub = (mt * 4 + jj) % 3;
        s_red[g][sub * 4 + kb][w] = make_float2(S, T);
      }
    }
  __syncthreads();

  // ---- wave w owns user w: combine waves, s_l = T/S, nu, store u_g
  float nu = 0.f;
#pragma unroll
  for (int l = 0; l < L; ++l) {
    float2 p0 = s_red[w][l][0], p1 = s_red[w][l][1];
    float2 p2 = s_red[w][l][2], p3 = s_red[w][l][3];
    float S = (p0.x + p1.x) + (p2.x + p3.x);
    float T = (p0.y + p1.y) + (p2.y + p3.y);
    nu += T * __frcp_rn(S) * wfv[l];
  }
  out[(b4 + w) * D + lane] = a3 * (a1 * uev + a2 * nu);
}

extern "C" void kernel_launch(void* const* d_in, const int* in_sizes, int n_in,
                              void* d_out, int out_size, void* d_ws, size_t ws_size,
                              hipStream_t stream) {
  const int* items = (const int*)d_in[0];
  const float* time_embs = (const float*)d_in[1];
  const float* user_emb = (const float*)d_in[2];
  const float* item_emb = (const float*)d_in[3];
  const float* cluster = (const float*)d_in[4];
  const float* wf = (const float*)d_in[5];
  const float* Wq = (const float*)d_in[6];
  const float* Wk = (const float*)d_in[7];
  const float* Wv = (const float*)d_in[8];
  const int* users = (const int*)d_in[9];
  const int* pos = (const int*)d_in[10];
  const int* neg = (const int*)d_in[11];
  const float* a1 = (const float*)d_in[12];
  const float* a2 = (const float*)d_in[13];
  const float* a3 = (const float*)d_in[14];
  const int B = in_sizes[9];
  const int NUG = B / G;

  short* Bf = (short*)d_ws;                      // [C*128] bf16 = 64 KB
  short* wsrows = Bf + C * 128;                  // [NUG*NROWS*64] bf16
  const int stage_blocks = (NUG * STAGE_ROWS + 15) / 16;
  hipLaunchKernelGGL(stage_pre, dim3(PRE_BLOCKS + stage_blocks), dim3(256), 0,
                     stream, cluster, Wk, Wq, Wv, items, time_embs, user_emb,
                     item_emb, users, pos, neg, Bf, wsrows, (float*)d_out, B, NUG);
  hipLaunchKernelGGL(gemm_main, dim3(NUG), dim3(256), 0, stream,
                     wsrows, Bf, user_emb, wf, users, a1, a2, a3,
                     (float*)d_out, B);
}

// Round 12
// 28.763 us; speedup vs baseline: 1.5390x; 1.0527x over previous
//
#include <hip/hip_runtime.h>

#define D 64
#define L 10
#define C 256
#define G 8
#define SWB 72  // bf16 LDS row stride in shorts (144 B, 16B-aligned)

typedef __attribute__((ext_vector_type(8))) short bf16x8;
typedef __attribute__((ext_vector_type(4))) short short4v;
typedef __attribute__((ext_vector_type(4))) float f32x4;

__device__ inline short f2bf(float f) {
  unsigned u = __float_as_uint(f);
  u = (u + 0x7FFFu + ((u >> 16) & 1u)) >> 16;
  return (short)u;
}
__device__ inline float4 add3(float4 a, float4 b, float4 c) {
  return make_float4(a.x + b.x + c.x, a.y + b.y + c.y, a.z + b.z + c.z, a.w + b.w + c.w);
}
__device__ inline short4v f2bf4(float4 a) {
  short4v r;
  r[0] = f2bf(a.x); r[1] = f2bf(a.y); r[2] = f2bf(a.z); r[3] = f2bf(a.w);
  return r;
}

// Coalesced pre (verified R8). Bf[c][k] = bf16(0.125*(cl@Wk@Wq^T)[c][k]),
// Bf[c][64+d] = bf16((cl@Wv)[c][d]).
__global__ __launch_bounds__(256) void pre(const float* __restrict__ cl,
                                           const float* __restrict__ Wk,
                                           const float* __restrict__ Wq,
                                           const float* __restrict__ Wv,
                                           short* __restrict__ Bf) {
  __shared__ float s_cl[4 * 64];
  __shared__ float s_kc[4 * 64];
  __shared__ float s_w[64 * 65];
  const int t = threadIdx.x;
  const int bh = blockIdx.x >> 6, cb = blockIdx.x & 63;
  const int c0 = cb * 4;
  const int r = t >> 6, j = t & 63;

  s_cl[t] = cl[c0 * 64 + t];
  if (bh == 0) {
#pragma unroll
    for (int i = 0; i < 4; ++i) {
      int e = i * 256 + t;
      float4 v = ((const float4*)Wq)[e];
      int k = e >> 4, q = e & 15;
      float* dst = &s_w[k * 65 + q * 4];
      dst[0] = v.x; dst[1] = v.y; dst[2] = v.z; dst[3] = v.w;
    }
  }
  __syncthreads();

  const float* __restrict__ Wx = bh ? Wv : Wk;
  float acc = 0.f;
#pragma unroll 8
  for (int m = 0; m < 64; ++m) acc += s_cl[r * 64 + m] * Wx[m * 64 + j];

  if (bh == 1) {
    Bf[(c0 + r) * 128 + 64 + j] = f2bf(acc);
    return;
  }
  s_kc[t] = acc;
  __syncthreads();

  float o = 0.f;
#pragma unroll 8
  for (int jj = 0; jj < 64; ++jj) o += s_kc[r * 64 + jj] * s_w[j * 65 + jj];
  Bf[(c0 + r) * 128 + j] = f2bf(0.125f * o);
}

// G=8 packing (generalizes verified R4-R8): slots p = mt*4 + jr, mt 0..5
// (24 slots, 3/user); g = p/3, l = (p%3)*4 + qr (valid l<10).
// In C/D space (row = kb*4+jj): p = mt*4+jj -> g compile-time; l = (p%3)*4+kb.
// ue tile rows 0..7 = users 0..7 (K = 64..127, V half).
__global__ __launch_bounds__(256) void filter_main(
    const int* __restrict__ items, const float* __restrict__ te,
    const float* __restrict__ ue_g, const float* __restrict__ ie_g,
    const float* __restrict__ wf_g, const short* __restrict__ Bf,
    const int* __restrict__ users, const int* __restrict__ pos_items,
    const int* __restrict__ neg_items, const float* __restrict__ a1p,
    const float* __restrict__ a2p, const float* __restrict__ a3p,
    float* __restrict__ out, int B) {
  __shared__ short s_shb[88 * SWB];   // 80 short rows + 8 ue rows, bf16
  __shared__ float2 s_red[G][12][4];  // [user][l][wave] -> (S,T)

  const int tid = threadIdx.x, w = tid >> 6, lane = tid & 63;
  const int col16 = lane & 15, kb = lane >> 4;
  const int qr = col16 >> 2, jr = col16 & 3;
  const int b8 = blockIdx.x * G;
  const int BD = B * D;

  // hoisted per-user long-latency loads: wave w owns users w and w+4
  const int uA = users[b8 + w], uB = users[b8 + 4 + w];
  const float uevA = ue_g[uA * D + lane];
  const float uevB = ue_g[uB * D + lane];
  const float posvA = ie_g[pos_items[b8 + w] * D + lane];
  const float posvB = ie_g[pos_items[b8 + 4 + w] * D + lane];
  const float negvA = ie_g[neg_items[b8 + w] * D + lane];
  const float negvB = ie_g[neg_items[b8 + 4 + w] * D + lane];
  float wfvA[L], wfvB[L];
#pragma unroll
  for (int l = 0; l < L; ++l) {
    wfvA[l] = wf_g[(uA * L + l) * D + lane];
    wfvB[l] = wf_g[(uB * L + l) * D + lane];
  }

  // ---- coalesced staging: 80 short rows + 8 ue rows -> bf16 LDS
  {
    const float4* te4 = (const float4*)te;
    const float4* ie4 = (const float4*)ie_g;
    const float4* ue4 = (const float4*)ue_g;
    const int grp = tid >> 4, j = tid & 15;
#pragma unroll
    for (int it = 0; it < 6; ++it) {
      int row = it * 16 + grp;
      if (row < 80) {
        int g = row / 10, l = row - g * 10;
        int u = users[b8 + g];
        int itm = items[u * L + l];
        float4 v = add3(te4[(u * L + l) * 16 + j], ie4[itm * 16 + j],
                        ue4[u * 16 + j]);
        *(short4v*)&s_shb[row * SWB + j * 4] = f2bf4(v);
      } else if (row < 88) {
        int u = users[b8 + (row - 80)];
        *(short4v*)&s_shb[row * SWB + j * 4] = f2bf4(ue4[u * 16 + j]);
      }
    }
  }
  __syncthreads();

  // ---- A fragments: pure ds_read_b128 from bf16 LDS (6 short tiles + ue)
  bf16x8 af[6][2];
  bf16x8 au0 = {}, au1 = {};
#pragma unroll
  for (int mt = 0; mt < 6; ++mt) {
    int p = mt * 4 + jr;
    int g = p / 3;
    int l = (p - g * 3) * 4 + qr;
    if (l < L) {
      const bf16x8* rp = (const bf16x8*)&s_shb[(g * 10 + l) * SWB];
      af[mt][0] = rp[kb];
      af[mt][1] = rp[4 + kb];
    } else {
      af[mt][0] = bf16x8{};
      af[mt][1] = bf16x8{};
    }
  }
  if (col16 < G) {
    const bf16x8* rp = (const bf16x8*)&s_shb[(80 + col16) * SWB];
    au0 = rp[kb];
    au1 = rp[4 + kb];
  }

  // ---- per-nt GEMM + softmax accumulation (no max-sub; fp32-safe range)
  float Sa[6][4], Ta[6][4];
#pragma unroll
  for (int mt = 0; mt < 6; ++mt)
#pragma unroll
    for (int jj = 0; jj < 4; ++jj) { Sa[mt][jj] = 0.f; Ta[mt][jj] = 0.f; }

#pragma unroll
  for (int nt = 0; nt < 4; ++nt) {
    const bf16x8* bp = (const bf16x8*)(Bf + ((w * 4 + nt) * 16 + col16) * 128);
    bf16x8 b0 = bp[kb], b1 = bp[4 + kb], b2 = bp[8 + kb], b3 = bp[12 + kb];
    f32x4 z = {0.f, 0.f, 0.f, 0.f};
    f32x4 cc[6];
    f32x4 cu = z;
#pragma unroll
    for (int mt = 0; mt < 6; ++mt) {
      cc[mt] = z;
      cc[mt] = __builtin_amdgcn_mfma_f32_16x16x32_bf16(af[mt][0], b0, cc[mt], 0, 0, 0);
      cc[mt] = __builtin_amdgcn_mfma_f32_16x16x32_bf16(af[mt][1], b1, cc[mt], 0, 0, 0);
    }
    cu = __builtin_amdgcn_mfma_f32_16x16x32_bf16(au0, b2, cu, 0, 0, 0);
    cu = __builtin_amdgcn_mfma_f32_16x16x32_bf16(au1, b3, cu, 0, 0, 0);
    // vu[g]: cu C/D row g -> reg g&3, lanes (g>>2)*16 + col16
    float vub[8];
#pragma unroll
    for (int g = 0; g < 8; ++g)
      vub[g] = __shfl(cu[g & 3], (g >> 2) * 16 + col16, 64);
#pragma unroll
    for (int mt = 0; mt < 6; ++mt)
#pragma unroll
      for (int jj = 0; jj < 4; ++jj) {
        float e = __expf(cc[mt][jj]);
        const int g = (mt * 4 + jj) / 3;  // compile-time
        Sa[mt][jj] += e;
        Ta[mt][jj] += e * vub[g];
      }
  }

  // ---- reduce over col16, write per-wave stats (l = (p%3)*4 + kb)
#pragma unroll
  for (int mt = 0; mt < 6; ++mt)
#pragma unroll
    for (int jj = 0; jj < 4; ++jj) {
      float S = Sa[mt][jj], T = Ta[mt][jj];
      S += __shfl_xor(S, 1, 64); T += __shfl_xor(T, 1, 64);
      S += __shfl_xor(S, 2, 64); T += __shfl_xor(T, 2, 64);
      S += __shfl_xor(S, 4, 64); T += __shfl_xor(T, 4, 64);
      S += __shfl_xor(S, 8, 64); T += __shfl_xor(T, 8, 64);
      if (col16 == 0) {
        const int g = (mt * 4 + jj) / 3, sub = (mt * 4 + jj) % 3;
        s_red[g][sub * 4 + kb][w] = make_float2(S, T);
      }
    }
  __syncthreads();

  // ---- wave w owns users w and w+4: combine waves, s_l = T/S, nu, outputs
  float nuA = 0.f, nuB = 0.f;
#pragma unroll
  for (int l = 0; l < L; ++l) {
    {
      float2 p0 = s_red[w][l][0], p1 = s_red[w][l][1];
      float2 p2 = s_red[w][l][2], p3 = s_red[w][l][3];
      float S = (p0.x + p1.x) + (p2.x + p3.x);
      float T = (p0.y + p1.y) + (p2.y + p3.y);
      nuA += T * __frcp_rn(S) * wfvA[l];
    }
    {
      float2 p0 = s_red[w + 4][l][0], p1 = s_red[w + 4][l][1];
      float2 p2 = s_red[w + 4][l][2], p3 = s_red[w + 4][l][3];
      float S = (p0.x + p1.x) + (p2.x + p3.x);
      float T = (p0.y + p1.y) + (p2.y + p3.y);
      nuB += T * __frcp_rn(S) * wfvB[l];
    }
  }
  const float a1 = *a1p, a2 = *a2p, a3 = *a3p;
  out[(b8 + w) * D + lane] = a3 * (a1 * uevA + a2 * nuA);
  out[(b8 + 4 + w) * D + lane] = a3 * (a1 * uevB + a2 * nuB);
  out[BD + (b8 + w) * D + lane] = posvA;
  out[BD + (b8 + 4 + w) * D + lane] = posvB;
  out[2 * BD + (b8 + w) * D + lane] = negvA;
  out[2 * BD + (b8 + 4 + w) * D + lane] = negvB;
}

extern "C" void kernel_launch(void* const* d_in, const int* in_sizes, int n_in,
                              void* d_out, int out_size, void* d_ws, size_t ws_size,
                              hipStream_t stream) {
  const int* items = (const int*)d_in[0];
  const float* time_embs = (const float*)d_in[1];
  const float* user_emb = (const float*)d_in[2];
  const float* item_emb = (const float*)d_in[3];
  const float* cluster = (const float*)d_in[4];
  const float* wf = (const float*)d_in[5];
  const float* Wq = (const float*)d_in[6];
  const float* Wk = (const float*)d_in[7];
  const float* Wv = (const float*)d_in[8];
  const int* users = (const int*)d_in[9];
  const int* pos = (const int*)d_in[10];
  const int* neg = (const int*)d_in[11];
  const float* a1 = (const float*)d_in[12];
  const float* a2 = (const float*)d_in[13];
  const float* a3 = (const float*)d_in[14];
  const int B = in_sizes[9];

  short* Bf = (short*)d_ws;  // [C][128] bf16
  hipLaunchKernelGGL(pre, dim3(128), dim3(256), 0, stream,
                     cluster, Wk, Wq, Wv, Bf);
  hipLaunchKernelGGL(filter_main, dim3(B / G), dim3(256), 0, stream,
                     items, time_embs, user_emb, item_emb, wf, Bf,
                     users, pos, neg, a1, a2, a3, (float*)d_out, B);
}